// Round 4
// baseline (13214.357 us; speedup 1.0000x reference)
//
#include <hip/hip_runtime.h>

#define IN_DIM   512
#define H_DIM    1024
#define OUT_DIM  256
#define B_DIM    64
#define S_DIM    256
#define EPS_F    1e-8f

#define GH       32   // workgroups per group
#define BPG      8    // batches per group
#define NTHREADS 512
#define NWG      256

// ---- LDS byte map (single A buffer: wave-private slices; no cross-wave reads)
#define AH_OFF   0        // h A-frags hi: [32 kt][4 kb][8 b] x16B = 16384
#define AL_OFF   16384    // h A-frags lo
#define XH_OFF   32768    // x A-frags hi: [16 kt'][4 kb][8 b] x16B = 8192
#define XL_OFF   40960    // x A-frags lo
#define SCH_OFF  49152    // h partials [2 par][8 kp][8 b][36 f32]
#define SCH_SZ   9216
#define SCX_OFF  67584    // iin partials [8 kp][8 b][36 f32]
#define SCY_OFF  76800    // y partials   [8 kp][8 b][9 f32]
#define IIN_OFF  79104    // iin [2 par][8 b][36 f32]
#define IIN_SZ   1152
#define LDS_BYTES 81408

#define OUT_Y_TOTAL ((size_t)B_DIM*S_DIM*OUT_DIM)

typedef float f32x4 __attribute__((ext_vector_type(4)));
typedef short s16x8 __attribute__((ext_vector_type(8)));

#define LGKM_FENCE() do { asm volatile("s_waitcnt lgkmcnt(0)" ::: "memory"); \
                          __builtin_amdgcn_sched_barrier(0); } while (0)

// ---- cache-bypassing (coherence-point) ops: sc0 sc1 -> serve at IF. The ONLY
// cross-XCD-visible accesses; no cache-invalidating fences anywhere.
__device__ __forceinline__ void st_u32_cc(unsigned* p, unsigned v) {
  asm volatile("global_store_dword %0, %1, off sc0 sc1" :: "v"(p), "v"(v) : "memory");
}
__device__ __forceinline__ void st_f32x4_cc(float* p, f32x4 v) {
  asm volatile("global_store_dwordx4 %0, %1, off sc0 sc1" :: "v"(p), "v"(v) : "memory");
}

// split f32 -> (bf16 hi, bf16 lo) by truncation; hi+lo reconstructs to ~2^-16 rel.
__device__ __forceinline__ void split_bf16(f32x4 f0, f32x4 f1, s16x8* hi, s16x8* lo) {
  union { unsigned u[4]; s16x8 s; } H, L;
  float fv[8];
#pragma unroll
  for (int e = 0; e < 4; ++e) { fv[e] = f0[e]; fv[e+4] = f1[e]; }
#pragma unroll
  for (int d = 0; d < 4; ++d) {
    unsigned u0 = __float_as_uint(fv[2*d]);
    unsigned u1 = __float_as_uint(fv[2*d+1]);
    unsigned t0 = u0 & 0xffff0000u, t1 = u1 & 0xffff0000u;
    H.u[d] = (u0 >> 16) | t1;
    L.u[d] = ((__float_as_uint(fv[2*d]   - __uint_as_float(t0))) >> 16)
           | ((__float_as_uint(fv[2*d+1] - __uint_as_float(t1))) & 0xffff0000u);
  }
  *hi = H.s; *lo = L.s;
}

__global__ void __launch_bounds__(NTHREADS, 2)
ltc_kernel(const float* __restrict__ x, const float* __restrict__ h0,
           const float* __restrict__ tspan, const float* __restrict__ tau,
           const float* __restrict__ Wiw, const float* __restrict__ Wib,
           const float* __restrict__ Wrw, const float* __restrict__ wmask,
           const float* __restrict__ Wow, const float* __restrict__ Wob,
           const float* __restrict__ alpha_p, const float* __restrict__ beta_p,
           const float* __restrict__ mu_p, const float* __restrict__ sigma_p,
           float* __restrict__ out,
           float* __restrict__ hb0, float* __restrict__ hb1,
           unsigned* __restrict__ flags)
{
  extern __shared__ char ldsc[];

  const int tid = threadIdx.x;
  const int wg  = blockIdx.x;
  const int g   = wg & 7;            // group id (XCD co-location heuristic only)
  const int w   = wg >> 3;           // 0..31 within group
  const int b0g = g * BPG;
  const int jw0 = w * 32;
  unsigned* flagp = flags + g*GH;

  const int lane = tid & 63;
  const int kp   = tid >> 6;         // wave id = K-part (8-way K split)

  // ---- W_rec B-frags (masked, split bf16) -> registers, permanent.
  s16x8 wbh[4][2], wbl[4][2];
#pragma unroll
  for (int i = 0; i < 4; ++i) {
    const int k0 = (kp*4 + i)*32 + (lane >> 4)*8;
#pragma unroll
    for (int nt = 0; nt < 2; ++nt) {
      const int j = jw0 + nt*16 + (lane & 15);
      const size_t go = (size_t)j*H_DIM + k0;
      f32x4 w0 = *(const f32x4*)(Wrw + go);
      f32x4 w1 = *(const f32x4*)(Wrw + go + 4);
      f32x4 m0 = *(const f32x4*)(wmask + go);
      f32x4 m1 = *(const f32x4*)(wmask + go + 4);
      w0 *= m0; w1 *= m1;
      split_bf16(w0, w1, &wbh[i][nt], &wbl[i][nt]);
    }
  }
  // ---- W_in B-frags (x-K split: wave kp covers k in [64kp, 64kp+64))
  s16x8 winh[2][2], winl[2][2];
#pragma unroll
  for (int i2 = 0; i2 < 2; ++i2) {
    const int k0 = (kp*2 + i2)*32 + (lane >> 4)*8;
#pragma unroll
    for (int nt = 0; nt < 2; ++nt) {
      const int j = jw0 + nt*16 + (lane & 15);
      const size_t go = (size_t)j*IN_DIM + k0;
      f32x4 w0 = *(const f32x4*)(Wiw + go);
      f32x4 w1 = *(const f32x4*)(Wiw + go + 4);
      split_bf16(w0, w1, &winh[i2][nt], &winl[i2][nt]);
    }
  }
  // ---- W_out B-frags (cols 0..7 real, 8..15 zero)
  s16x8 woh[4], wol[4];
  {
    const s16x8 z8 = {0,0,0,0,0,0,0,0};
#pragma unroll
    for (int i = 0; i < 4; ++i) {
      if ((lane & 15) < 8) {
        const int k0 = (kp*4 + i)*32 + (lane >> 4)*8;
        const size_t go = (size_t)(w*8 + (lane & 15))*H_DIM + k0;
        f32x4 w0 = *(const f32x4*)(Wow + go);
        f32x4 w1 = *(const f32x4*)(Wow + go + 4);
        split_bf16(w0, w1, &woh[i], &wol[i]);
      } else { woh[i] = z8; wol[i] = z8; }
    }
  }

  // ---- per-lane epilogue mapping (used by waves 0/1/2)
  const int b_e = lane >> 3;               // 0..7
  const int j4l = (lane & 7) * 4;          // 0,4,..,28
  const int gj  = jw0 + j4l;
  const int gb  = b0g + b_e;
  f32x4 mu4 = *(const f32x4*)(mu_p + gj);
  f32x4 sg4 = *(const f32x4*)(sigma_p + gj);
  f32x4 al4 = *(const f32x4*)(alpha_p + gj);
  f32x4 be4 = *(const f32x4*)(beta_p + gj);
  f32x4 ta4 = *(const f32x4*)(tau + gj);
  f32x4 wib4 = *(const f32x4*)(Wib + gj);
  f32x4 sgi4, ti4;
#pragma unroll
  for (int e = 0; e < 4; ++e) { sgi4[e] = 1.0f/(sg4[e]+EPS_F); ti4[e] = 1.0f/ta4[e]; }
  const float wob_s = Wob[w*8 + (lane & 7)];
  f32x4 hold4 = *(const f32x4*)(h0 + (size_t)gb*H_DIM + gj);
  float tsc = tspan[(size_t)gb*S_DIM + 0] * (1.0f/6.0f);

  // ---- helpers -------------------------------------------------------------
  auto poll4 = [&](unsigned ph) {          // wait for this wave's 4 producers
    const unsigned* fp4 = flagp + 4*kp;
    for (;;) {
      f32x4 r;
      asm volatile("global_load_dwordx4 %0, %1, off sc0 sc1\n\ts_waitcnt vmcnt(0)"
                   : "=v"(r) : "v"(fp4) : "memory");
      if (__float_as_uint(r.x) >= ph && __float_as_uint(r.y) >= ph &&
          __float_as_uint(r.z) >= ph && __float_as_uint(r.w) >= ph) break;
      __builtin_amdgcn_s_sleep(1);
    }
  };

  auto stage_h = [&](const float* hsrc) {  // wave-private k-slice -> A-frags
    const int b = lane & 7, kb = (lane >> 3) & 3, i0 = lane >> 5;
    const float* s0 = hsrc + (size_t)(b0g + b)*H_DIM + (4*kp + i0)*32 + kb*8;
    f32x4 r0, r1, r2, r3;
    asm volatile(
      "global_load_dwordx4 %0, %4, off sc0 sc1\n\t"
      "global_load_dwordx4 %1, %5, off sc0 sc1\n\t"
      "global_load_dwordx4 %2, %6, off sc0 sc1\n\t"
      "global_load_dwordx4 %3, %7, off sc0 sc1\n\t"
      "s_waitcnt vmcnt(0)"
      : "=&v"(r0), "=&v"(r1), "=&v"(r2), "=&v"(r3)
      : "v"(s0), "v"(s0+4), "v"(s0+64), "v"(s0+68) : "memory");
    s16x8 h1, l1, h2, l2;
    split_bf16(r0, r1, &h1, &l1);
    split_bf16(r2, r3, &h2, &l2);
    char* d = ldsc + kp*2048 + lane*16;
    *(s16x8*)(d + AH_OFF)        = h1;  *(s16x8*)(d + AL_OFF)        = l1;
    *(s16x8*)(d + AH_OFF + 1024) = h2;  *(s16x8*)(d + AL_OFF + 1024) = l2;
  };

  auto stage_x = [&](int tt) {             // x(tt) wave k-slice -> x A-frags
    const int b = lane & 7, kb = (lane >> 3) & 3, i0 = lane >> 5;
    const float* s0 = x + ((size_t)(b0g + b)*S_DIM + tt)*IN_DIM + (2*kp + i0)*32 + kb*8;
    f32x4 v0 = *(const f32x4*)s0;
    f32x4 v1 = *(const f32x4*)(s0 + 4);
    s16x8 hh, ll;
    split_bf16(v0, v1, &hh, &ll);
    char* d = ldsc + kp*1024 + lane*16;
    *(s16x8*)(d + XH_OFF) = hh;  *(s16x8*)(d + XL_OFF) = ll;
  };

  auto mfma_iin = [&](f32x4& ax0, f32x4& ax1) {
    const char* Xb = ldsc + kp*1024 + (lane >> 4)*128 + (lane & 7)*16;
#pragma unroll
    for (int i2 = 0; i2 < 2; ++i2) {
      s16x8 xh = *(const s16x8*)(Xb + XH_OFF + i2*512);
      s16x8 xl = *(const s16x8*)(Xb + XL_OFF + i2*512);
      ax0 = __builtin_amdgcn_mfma_f32_16x16x32_bf16(xh, winh[i2][0], ax0, 0,0,0);
      ax0 = __builtin_amdgcn_mfma_f32_16x16x32_bf16(xl, winh[i2][0], ax0, 0,0,0);
      ax0 = __builtin_amdgcn_mfma_f32_16x16x32_bf16(xh, winl[i2][0], ax0, 0,0,0);
      ax1 = __builtin_amdgcn_mfma_f32_16x16x32_bf16(xh, winh[i2][1], ax1, 0,0,0);
      ax1 = __builtin_amdgcn_mfma_f32_16x16x32_bf16(xl, winh[i2][1], ax1, 0,0,0);
      ax1 = __builtin_amdgcn_mfma_f32_16x16x32_bf16(xh, winl[i2][1], ax1, 0,0,0);
    }
  };
  // --------------------------------------------------------------------------

  // ---- init: h0 -> hb1 (coherent) by wave0; flag=1; x(0) staged; iin(0) computed
  if (kp == 0) {
    st_f32x4_cc(hb1 + (size_t)gb*H_DIM + gj, hold4);
    asm volatile("s_waitcnt vmcnt(0)" ::: "memory");
    if (tid == 0) st_u32_cc(flagp + w, 1u);
  }
  stage_x(0);
  LGKM_FENCE();
  {
    f32x4 ax0 = {0.f,0.f,0.f,0.f}, ax1 = {0.f,0.f,0.f,0.f};
    mfma_iin(ax0, ax1);
    if (lane < 32) {
      const int brow = (lane >> 4)*4, l15 = lane & 15;
      float* scx = (float*)(ldsc + SCX_OFF) + kp*288;
#pragma unroll
      for (int q = 0; q < 4; ++q) {
        scx[(brow+q)*36 + l15]      = ax0[q];
        scx[(brow+q)*36 + 16 + l15] = ax1[q];
      }
    }
  }
  __syncthreads();
  if (kp == 1) {
    const float* scx = (float*)(ldsc + SCX_OFF);
    f32x4 s = wib4;
#pragma unroll
    for (int k2 = 0; k2 < 8; ++k2) s += *(const f32x4*)(scx + k2*288 + b_e*36 + j4l);
    *(f32x4*)(ldsc + IIN_OFF + (b_e*36 + j4l)*4) = s;
  }

  unsigned p = 1;
  for (int t = 0; t < S_DIM; ++t) {
#pragma unroll 1
    for (int u = 0; u < 6; ++u, ++p) {
      poll4(p);
      stage_h((p & 1) ? hb1 : hb0);
      const bool doX = (u == 2) && (t < S_DIM-1);
      const bool doI = (u == 3) && (t < S_DIM-1);
      const bool doY = (u == 0);
      if (doX) stage_x(t+1);
      LGKM_FENCE();

      // ---- MFMA: 3-split bf16 (hi*hi + lo*hi + hi*lo), B from registers
      f32x4 acc0 = {0.f,0.f,0.f,0.f}, acc1 = {0.f,0.f,0.f,0.f};
      f32x4 accy = {0.f,0.f,0.f,0.f};
      const char* Ab = ldsc + kp*2048 + (lane >> 4)*128 + (lane & 7)*16;
#pragma unroll
      for (int i = 0; i < 4; ++i) {
        s16x8 ah = *(const s16x8*)(Ab + AH_OFF + i*512);
        s16x8 al = *(const s16x8*)(Ab + AL_OFF + i*512);
        acc0 = __builtin_amdgcn_mfma_f32_16x16x32_bf16(ah, wbh[i][0], acc0, 0,0,0);
        acc0 = __builtin_amdgcn_mfma_f32_16x16x32_bf16(al, wbh[i][0], acc0, 0,0,0);
        acc0 = __builtin_amdgcn_mfma_f32_16x16x32_bf16(ah, wbl[i][0], acc0, 0,0,0);
        acc1 = __builtin_amdgcn_mfma_f32_16x16x32_bf16(ah, wbh[i][1], acc1, 0,0,0);
        acc1 = __builtin_amdgcn_mfma_f32_16x16x32_bf16(al, wbh[i][1], acc1, 0,0,0);
        acc1 = __builtin_amdgcn_mfma_f32_16x16x32_bf16(ah, wbl[i][1], acc1, 0,0,0);
        if (doY) {
          accy = __builtin_amdgcn_mfma_f32_16x16x32_bf16(ah, woh[i], accy, 0,0,0);
          accy = __builtin_amdgcn_mfma_f32_16x16x32_bf16(al, woh[i], accy, 0,0,0);
          accy = __builtin_amdgcn_mfma_f32_16x16x32_bf16(ah, wol[i], accy, 0,0,0);
        }
      }
      f32x4 ax0 = {0.f,0.f,0.f,0.f}, ax1 = {0.f,0.f,0.f,0.f};
      if (doI) mfma_iin(ax0, ax1);

      // ---- partials -> scratch
      if (lane < 32) {
        const int brow = (lane >> 4)*4, l15 = lane & 15;
        float* sch = (float*)(ldsc + SCH_OFF + (p & 1)*SCH_SZ) + kp*288;
#pragma unroll
        for (int q = 0; q < 4; ++q) {
          sch[(brow+q)*36 + l15]      = acc0[q];
          sch[(brow+q)*36 + 16 + l15] = acc1[q];
        }
        if (doY && l15 < 8) {
          float* scy = (float*)(ldsc + SCY_OFF) + kp*72;
#pragma unroll
          for (int q = 0; q < 4; ++q) scy[(brow+q)*9 + l15] = accy[q];
        }
        if (doI) {
          float* scx = (float*)(ldsc + SCX_OFF) + kp*288;
#pragma unroll
          for (int q = 0; q < 4; ++q) {
            scx[(brow+q)*36 + l15]      = ax0[q];
            scx[(brow+q)*36 + 16 + l15] = ax1[q];
          }
        }
      }
      __syncthreads();

      // ---- wave roles (parallel)
      if (kp == 0) {
        // h epilogue: reduce K-parts, sigmoid, ODE update, coherent store, flag
        const float* sch = (const float*)(ldsc + SCH_OFF + (p & 1)*SCH_SZ);
        f32x4 ir = {0.f,0.f,0.f,0.f};
#pragma unroll
        for (int k2 = 0; k2 < 8; ++k2) ir += *(const f32x4*)(sch + k2*288 + b_e*36 + j4l);
        f32x4 iin4 = *(const f32x4*)(ldsc + IIN_OFF + (t & 1)*IIN_SZ + (b_e*36 + j4l)*4);
        f32x4 hn;
#pragma unroll
        for (int e = 0; e < 4; ++e) {
          const float z  = (ir[e] - mu4[e]) * sgi4[e];
          const float f  = 1.0f / (1.0f + __expf(-z));
          const float dh = -al4[e]*hold4[e] + be4[e]*f*(iin4[e] + ir[e]);
          hn[e] = hold4[e] + tsc*dh*ti4[e];
        }
        float* hdst = ((p+1) & 1) ? hb1 : hb0;
        st_f32x4_cc(hdst + (size_t)gb*H_DIM + gj, hn);
        asm volatile("s_waitcnt vmcnt(0)" ::: "memory");
        if (tid == 0) st_u32_cc(flagp + w, p + 1);
        hold4 = hn;
        if (u == 5) {
          if (t < S_DIM-1) tsc = tspan[(size_t)gb*S_DIM + t + 1] * (1.0f/6.0f);
          else *(f32x4*)(out + OUT_Y_TOTAL + (size_t)gb*H_DIM + gj) = hn;
        }
      } else if (kp == 1 && doI) {
        // iin(t+1) reduce (parallel with wave0's epilogue)
        const float* scx = (const float*)(ldsc + SCX_OFF);
        f32x4 s = wib4;
#pragma unroll
        for (int k2 = 0; k2 < 8; ++k2) s += *(const f32x4*)(scx + k2*288 + b_e*36 + j4l);
        *(f32x4*)(ldsc + IIN_OFF + ((t+1) & 1)*IIN_SZ + (b_e*36 + j4l)*4) = s;
      } else if (kp == 2 && doY && t > 0) {
        // y(t-1) reduce + store
        const float* scy = (const float*)(ldsc + SCY_OFF);
        float s = wob_s;
#pragma unroll
        for (int k2 = 0; k2 < 8; ++k2) s += scy[k2*72 + b_e*9 + (lane & 7)];
        out[((size_t)gb*S_DIM + (t-1))*OUT_DIM + w*8 + (lane & 7)] = s;
      }
    }
  }

  // ---- tail: y(S-1) needs one more stage of h_end
  poll4(p);                    // p == 1537
  stage_h(hb1);
  LGKM_FENCE();
  {
    f32x4 accy = {0.f,0.f,0.f,0.f};
    const char* Ab = ldsc + kp*2048 + (lane >> 4)*128 + (lane & 7)*16;
#pragma unroll
    for (int i = 0; i < 4; ++i) {
      s16x8 ah = *(const s16x8*)(Ab + AH_OFF + i*512);
      s16x8 al = *(const s16x8*)(Ab + AL_OFF + i*512);
      accy = __builtin_amdgcn_mfma_f32_16x16x32_bf16(ah, woh[i], accy, 0,0,0);
      accy = __builtin_amdgcn_mfma_f32_16x16x32_bf16(al, woh[i], accy, 0,0,0);
      accy = __builtin_amdgcn_mfma_f32_16x16x32_bf16(ah, wol[i], accy, 0,0,0);
    }
    if (lane < 32 && (lane & 15) < 8) {
      const int brow = (lane >> 4)*4, l15 = lane & 15;
      float* scy = (float*)(ldsc + SCY_OFF) + kp*72;
#pragma unroll
      for (int q = 0; q < 4; ++q) scy[(brow+q)*9 + l15] = accy[q];
    }
  }
  __syncthreads();
  if (kp == 2) {
    const float* scy = (const float*)(ldsc + SCY_OFF);
    float s = wob_s;
#pragma unroll
    for (int k2 = 0; k2 < 8; ++k2) s += scy[k2*72 + b_e*9 + (lane & 7)];
    out[((size_t)gb*S_DIM + (S_DIM-1))*OUT_DIM + w*8 + (lane & 7)] = s;
  }
}

extern "C" void kernel_launch(void* const* d_in, const int* in_sizes, int n_in,
                              void* d_out, int out_size, void* d_ws, size_t ws_size,
                              hipStream_t stream) {
  const float* x    = (const float*)d_in[0];
  const float* h0   = (const float*)d_in[1];
  const float* ts   = (const float*)d_in[2];
  const float* tau  = (const float*)d_in[3];
  const float* Wiw  = (const float*)d_in[4];
  const float* Wib  = (const float*)d_in[5];
  const float* Wrw  = (const float*)d_in[6];
  const float* msk  = (const float*)d_in[7];
  const float* Wow  = (const float*)d_in[8];
  const float* Wob  = (const float*)d_in[9];
  const float* alp  = (const float*)d_in[10];
  const float* bet  = (const float*)d_in[11];
  const float* mu   = (const float*)d_in[12];
  const float* sg   = (const float*)d_in[13];
  float* out = (float*)d_out;

  char* ws = (char*)d_ws;
  float* hb0 = (float*)(ws);
  float* hb1 = (float*)(ws + 262144);
  unsigned* flg = (unsigned*)(ws + 786432);

  hipMemsetAsync(flg, 0, 4096, stream);   // flags must start at 0 every call

  hipFuncSetAttribute((const void*)ltc_kernel,
                      hipFuncAttributeMaxDynamicSharedMemorySize, LDS_BYTES);

  void* args[] = { (void*)&x, (void*)&h0, (void*)&ts, (void*)&tau,
                   (void*)&Wiw, (void*)&Wib, (void*)&Wrw, (void*)&msk,
                   (void*)&Wow, (void*)&Wob, (void*)&alp, (void*)&bet,
                   (void*)&mu, (void*)&sg, (void*)&out,
                   (void*)&hb0, (void*)&hb1, (void*)&flg };
  hipLaunchCooperativeKernel((const void*)ltc_kernel, dim3(NWG), dim3(NTHREADS),
                             args, LDS_BYTES, stream);
}

// Round 5
// 7143.093 us; speedup vs baseline: 1.8499x; 1.8499x over previous
//
#include <hip/hip_runtime.h>

#define IN_DIM   512
#define H_DIM    1024
#define OUT_DIM  256
#define B_DIM    64
#define S_DIM    256
#define EPS_F    1e-8f

#define BPG      8      // batches per group
#define NTHREADS 512
#define NWG      256    // one WG per CU
#define SLOT_STRIDE 65536   // u32 elements per exchange slot (64*1024)

#define OUT_Y_TOTAL ((size_t)B_DIM*S_DIM*OUT_DIM)

typedef float    f32x4 __attribute__((ext_vector_type(4)));
typedef unsigned u32x4 __attribute__((ext_vector_type(4)));
typedef short    s16x8 __attribute__((ext_vector_type(8)));

#define MFMA16 __builtin_amdgcn_mfma_f32_16x16x32_bf16

union B8 { unsigned u[4]; s16x8 v; };

// split f32 -> (bf16 hi, bf16 lo) by truncation; hi+lo reconstructs to ~2^-16 rel.
__device__ __forceinline__ void split_bf16(f32x4 f0, f32x4 f1, s16x8* hi, s16x8* lo) {
  B8 H, L;
  float fv[8];
#pragma unroll
  for (int e = 0; e < 4; ++e) { fv[e] = f0[e]; fv[e+4] = f1[e]; }
#pragma unroll
  for (int d = 0; d < 4; ++d) {
    unsigned u0 = __float_as_uint(fv[2*d]);
    unsigned u1 = __float_as_uint(fv[2*d+1]);
    unsigned t0 = u0 & 0xffff0000u, t1 = u1 & 0xffff0000u;
    H.u[d] = (u0 >> 16) | t1;
    L.u[d] = ((__float_as_uint(fv[2*d]   - __uint_as_float(t0))) >> 16)
           | ((__float_as_uint(fv[2*d+1] - __uint_as_float(t1))) & 0xffff0000u);
  }
  *hi = H.v; *lo = L.v;
}

// exchange word: [hi bf16 | lo bf16], 3-bit tag in low bits of word0 of each 16B granule
__device__ __forceinline__ u32x4 enc_h(f32x4 hn, unsigned tag) {
  u32x4 e;
#pragma unroll
  for (int k = 0; k < 4; ++k) {
    unsigned uh = __float_as_uint(hn[k]) & 0xFFFF0000u;
    float r = hn[k] - __uint_as_float(uh);
    e[k] = uh | (__float_as_uint(r) >> 16);
  }
  e.x = (e.x & ~7u) | tag;
  return e;
}

__device__ __forceinline__ s16x8 pack_hi(u32x4 a, u32x4 b) {
  B8 t;
  t.u[0] = (a.y & 0xFFFF0000u) | (a.x >> 16);
  t.u[1] = (a.w & 0xFFFF0000u) | (a.z >> 16);
  t.u[2] = (b.y & 0xFFFF0000u) | (b.x >> 16);
  t.u[3] = (b.w & 0xFFFF0000u) | (b.z >> 16);
  return t.v;
}
__device__ __forceinline__ s16x8 pack_lo(u32x4 a, u32x4 b) {
  B8 t;
  t.u[0] = (a.y << 16) | (a.x & 0xFFF8u);   // strip 3 tag bits (word0 of granule)
  t.u[1] = (a.w << 16) | (a.z & 0xFFFFu);
  t.u[2] = (b.y << 16) | (b.x & 0xFFF8u);
  t.u[3] = (b.w << 16) | (b.z & 0xFFFFu);
  return t.v;
}

__global__ void __launch_bounds__(NTHREADS)
ltc_kernel(const float* __restrict__ x, const float* __restrict__ h0,
           const float* __restrict__ tspan, const float* __restrict__ tau,
           const float* __restrict__ Wiw, const float* __restrict__ Wib,
           const float* __restrict__ Wrw, const float* __restrict__ wmask,
           const float* __restrict__ Wow, const float* __restrict__ Wob,
           const float* __restrict__ alpha_p, const float* __restrict__ beta_p,
           const float* __restrict__ mu_p, const float* __restrict__ sigma_p,
           float* __restrict__ out, unsigned* __restrict__ hb)
{
  __shared__ __align__(16) float sch[2][8][8][36];  // [slot][kp][b][j] h partials
  __shared__ __align__(16) float scx[8][8][36];     // iin partials
  __shared__ __align__(16) float scy[8][8][9];      // y partials

  const int tid = threadIdx.x;
  const int wg  = blockIdx.x;
  const int g   = wg & 7;           // group (XCD heuristic only)
  const int w   = wg >> 3;          // 0..31 within group
  const int b0g = g * BPG;
  const int jw0 = w * 32;
  const int l   = tid & 63;
  const int v   = tid >> 6;         // wave id: K-part (consumer), batch owner (producer)
  const int gb_v = b0g + v;
  const int le  = l & 7;
  const int j4  = jw0 + 4*le;

  // ---- W_rec B-frags (masked, split bf16) -> registers, permanent
  s16x8 wbh[4][2], wbl[4][2];
#pragma unroll
  for (int i = 0; i < 4; ++i) {
    const int k0 = v*128 + i*32 + ((l >> 4) << 3);
#pragma unroll
    for (int nt = 0; nt < 2; ++nt) {
      const size_t go = (size_t)(jw0 + nt*16 + (l & 15))*H_DIM + k0;
      f32x4 w0 = *(const f32x4*)(Wrw + go)     * *(const f32x4*)(wmask + go);
      f32x4 w1 = *(const f32x4*)(Wrw + go + 4) * *(const f32x4*)(wmask + go + 4);
      split_bf16(w0, w1, &wbh[i][nt], &wbl[i][nt]);
    }
  }
  // ---- W_out B-frags (cols 0..7 real, 8..15 zero), permanent
  s16x8 woh[4], wol[4];
#pragma unroll
  for (int i = 0; i < 4; ++i) {
    const int k0 = v*128 + i*32 + ((l >> 4) << 3);
    if ((l & 15) < 8) {
      const size_t go = (size_t)(w*8 + (l & 15))*H_DIM + k0;
      split_bf16(*(const f32x4*)(Wow + go), *(const f32x4*)(Wow + go + 4),
                 &woh[i], &wol[i]);
    } else {
      B8 z; z.u[0] = z.u[1] = z.u[2] = z.u[3] = 0;
      woh[i] = z.v; wol[i] = z.v;
    }
  }

  // ---- per-lane (lanes 0..7) epilogue state for batch b=v
  f32x4 mu4  = *(const f32x4*)(mu_p + j4);
  f32x4 sg4  = *(const f32x4*)(sigma_p + j4);
  f32x4 al4  = *(const f32x4*)(alpha_p + j4);
  f32x4 be4  = *(const f32x4*)(beta_p + j4);
  f32x4 ta4  = *(const f32x4*)(tau + j4);
  f32x4 wib4 = *(const f32x4*)(Wib + j4);
  f32x4 sgi4, ti4;
#pragma unroll
  for (int e = 0; e < 4; ++e) { sgi4[e] = 1.0f/(sg4[e]+EPS_F); ti4[e] = 1.0f/ta4[e]; }
  const float wob_s = Wob[w*8 + le];
  f32x4 hold4 = *(const f32x4*)(h0 + ((size_t)gb_v << 10) + j4);
  float tsc = tspan[(size_t)gb_v*S_DIM] * (1.0f/6.0f);

  // ---- phase 0: publish tagged h0 (slot 0, tag 0)
  if (l < 8) {
    u32x4 e0 = enc_h(hold4, 0u);
    unsigned* dst = hb + ((unsigned)gb_v << 10) + j4;
    asm volatile("global_store_dwordx4 %0, %1, off sc0 sc1"
                 :: "v"(dst), "v"(e0) : "memory");
  }

  // ---- iin partial MFMA for time tt (x and Win loaded fresh, plain/cached)
  auto iin_partials = [&](int tt, f32x4& ax0, f32x4& ax1) {
    const int bL = l & 7, ko = (l >> 4) << 3;
    const float* xp = x + ((size_t)(b0g + bL)*S_DIM + tt)*IN_DIM + v*64 + ko;
    f32x4 xq0 = *(const f32x4*)xp,        xq1 = *(const f32x4*)(xp + 4);
    f32x4 xq2 = *(const f32x4*)(xp + 32), xq3 = *(const f32x4*)(xp + 36);
    const int jn0 = jw0 + (l & 15);
#pragma unroll
    for (int i2 = 0; i2 < 2; ++i2) {
      s16x8 xh, xl;
      split_bf16(i2 ? xq2 : xq0, i2 ? xq3 : xq1, &xh, &xl);
#pragma unroll
      for (int nt = 0; nt < 2; ++nt) {
        const float* wp = Wiw + (size_t)(jn0 + nt*16)*IN_DIM + v*64 + i2*32 + ko;
        s16x8 wh, wl;
        split_bf16(*(const f32x4*)wp, *(const f32x4*)(wp + 4), &wh, &wl);
        if (nt == 0) {
          ax0 = MFMA16(xh, wh, ax0, 0,0,0);
          ax0 = MFMA16(xl, wh, ax0, 0,0,0);
          ax0 = MFMA16(xh, wl, ax0, 0,0,0);
        } else {
          ax1 = MFMA16(xh, wh, ax1, 0,0,0);
          ax1 = MFMA16(xl, wh, ax1, 0,0,0);
          ax1 = MFMA16(xh, wl, ax1, 0,0,0);
        }
      }
    }
  };

  // ---- pre-loop: iin(0) -> registers
  f32x4 iin4 = {0.f,0.f,0.f,0.f}, iin_nx = {0.f,0.f,0.f,0.f};
  {
    f32x4 ax0 = {0.f,0.f,0.f,0.f}, ax1 = {0.f,0.f,0.f,0.f};
    iin_partials(0, ax0, ax1);
    if (l < 32) {
      const int brow = (l >> 4) * 4, l15 = l & 15;
      float* scxp = &scx[v][brow][l15];
#pragma unroll
      for (int qq = 0; qq < 4; ++qq) { scxp[qq*36] = ax0[qq]; scxp[qq*36 + 16] = ax1[qq]; }
    }
    __syncthreads();
    if (l < 8) {
      f32x4 s = wib4;
#pragma unroll
      for (int k2 = 0; k2 < 8; ++k2) s += *(const f32x4*)&scx[k2][v][4*le];
      iin4 = s;
    }
    __syncthreads();
  }

  unsigned p = 1;
#pragma unroll 1
  for (int t = 0; t < S_DIM; ++t) {
#pragma unroll 1
    for (int u = 0; u < 6; ++u, ++p) {
      const unsigned slotC = (p-1) & 1, tagC = (p-1) & 3;
      const unsigned slotP = p & 1,     tagP = p & 3;
      const bool doY = (u == 0);
      const bool doX = (u == 3) && (t + 1 < S_DIM);

      // ---- speculative tagged A-frag load (direct to registers, retry)
      u32x4 q0,q1,q2,q3,q4,q5,q6,q7;
      {
        const unsigned* ap = hb + slotC*SLOT_STRIDE
                           + ((unsigned)(b0g + (l & 7)) << 10)
                           + (unsigned)(v*128 + ((l >> 4) << 3));
        for (;;) {
          int ok;
          if ((l & 15) < 8) {
            asm volatile(
              "global_load_dwordx4 %0, %8, off sc0 sc1\n\t"
              "global_load_dwordx4 %1, %8, off offset:16 sc0 sc1\n\t"
              "global_load_dwordx4 %2, %8, off offset:128 sc0 sc1\n\t"
              "global_load_dwordx4 %3, %8, off offset:144 sc0 sc1\n\t"
              "global_load_dwordx4 %4, %8, off offset:256 sc0 sc1\n\t"
              "global_load_dwordx4 %5, %8, off offset:272 sc0 sc1\n\t"
              "global_load_dwordx4 %6, %8, off offset:384 sc0 sc1\n\t"
              "global_load_dwordx4 %7, %8, off offset:400 sc0 sc1\n\t"
              "s_waitcnt vmcnt(0)"
              : "=&v"(q0), "=&v"(q1), "=&v"(q2), "=&v"(q3),
                "=&v"(q4), "=&v"(q5), "=&v"(q6), "=&v"(q7)
              : "v"(ap) : "memory");
            ok = ((q0.x & 7u) == tagC) & ((q1.x & 7u) == tagC) &
                 ((q2.x & 7u) == tagC) & ((q3.x & 7u) == tagC) &
                 ((q4.x & 7u) == tagC) & ((q5.x & 7u) == tagC) &
                 ((q6.x & 7u) == tagC) & ((q7.x & 7u) == tagC);
          } else ok = 1;
          if (__all(ok)) break;
          __builtin_amdgcn_s_sleep(2);
        }
      }

      // ---- MFMA: 3-split bf16 (hh + lh + hl), B from registers
      f32x4 acc0 = {0.f,0.f,0.f,0.f}, acc1 = {0.f,0.f,0.f,0.f};
      f32x4 accy = {0.f,0.f,0.f,0.f};
#pragma unroll
      for (int i = 0; i < 4; ++i) {
        u32x4 qa = (i==0) ? q0 : (i==1) ? q2 : (i==2) ? q4 : q6;
        u32x4 qb = (i==0) ? q1 : (i==1) ? q3 : (i==2) ? q5 : q7;
        s16x8 ah = pack_hi(qa, qb), al = pack_lo(qa, qb);
        acc0 = MFMA16(ah, wbh[i][0], acc0, 0,0,0);
        acc0 = MFMA16(al, wbh[i][0], acc0, 0,0,0);
        acc0 = MFMA16(ah, wbl[i][0], acc0, 0,0,0);
        acc1 = MFMA16(ah, wbh[i][1], acc1, 0,0,0);
        acc1 = MFMA16(al, wbh[i][1], acc1, 0,0,0);
        acc1 = MFMA16(ah, wbl[i][1], acc1, 0,0,0);
        if (doY) {
          accy = MFMA16(ah, woh[i], accy, 0,0,0);
          accy = MFMA16(al, woh[i], accy, 0,0,0);
          accy = MFMA16(ah, wol[i], accy, 0,0,0);
        }
      }
      f32x4 ax0 = {0.f,0.f,0.f,0.f}, ax1 = {0.f,0.f,0.f,0.f};
      if (doX) iin_partials(t + 1, ax0, ax1);

      // ---- partials -> LDS scratch
      if (l < 32) {
        const int brow = (l >> 4) * 4, l15 = l & 15;
        float* schp = &sch[slotP][v][brow][l15];
#pragma unroll
        for (int qq = 0; qq < 4; ++qq) { schp[qq*36] = acc0[qq]; schp[qq*36 + 16] = acc1[qq]; }
        if (doX) {
          float* scxp = &scx[v][brow][l15];
#pragma unroll
          for (int qq = 0; qq < 4; ++qq) { scxp[qq*36] = ax0[qq]; scxp[qq*36 + 16] = ax1[qq]; }
        }
        if (doY && l15 < 8) {
          float* scyp = &scy[v][brow][l15];
#pragma unroll
          for (int qq = 0; qq < 4; ++qq) scyp[qq*9] = accy[qq];
        }
      }
      __syncthreads();

      // ---- distributed epilogue: wave v owns batch b=v (lanes 0..7)
      if (l < 8) {
        f32x4 ir = {0.f,0.f,0.f,0.f};
#pragma unroll
        for (int k2 = 0; k2 < 8; ++k2) ir += *(const f32x4*)&sch[slotP][k2][v][4*le];
        f32x4 hn;
#pragma unroll
        for (int e = 0; e < 4; ++e) {
          const float z  = (ir[e] - mu4[e]) * sgi4[e];
          const float f  = 1.0f / (1.0f + __expf(-z));
          const float dh = -al4[e]*hold4[e] + be4[e]*f*(iin4[e] + ir[e]);
          hn[e] = hold4[e] + tsc*dh*ti4[e];
        }
        hold4 = hn;
        u32x4 enc = enc_h(hn, tagP);
        unsigned* dst = hb + slotP*SLOT_STRIDE + ((unsigned)gb_v << 10) + j4;
        asm volatile("global_store_dwordx4 %0, %1, off sc0 sc1"
                     :: "v"(dst), "v"(enc) : "memory");
        if (doY && t > 0) {
          float s = wob_s;
#pragma unroll
          for (int k2 = 0; k2 < 8; ++k2) s += scy[k2][v][le];
          out[((size_t)gb_v*S_DIM + (t-1))*OUT_DIM + w*8 + le] = s;
        }
        if (doX) {
          f32x4 s = wib4;
#pragma unroll
          for (int k2 = 0; k2 < 8; ++k2) s += *(const f32x4*)&scx[k2][v][4*le];
          iin_nx = s;
        }
        if (u == 5) {
          if (t + 1 < S_DIM) {
            tsc = tspan[(size_t)gb_v*S_DIM + t + 1] * (1.0f/6.0f);
            iin4 = iin_nx;
          } else {
            *(f32x4*)(out + OUT_Y_TOTAL + ((size_t)gb_v << 10) + j4) = hn;
          }
        }
      }
    }
  }

  // ---- tail: y(S-1) from final h (phase 1536)
  {
    const unsigned slotC = (p-1) & 1, tagC = (p-1) & 3;
    u32x4 q0,q1,q2,q3,q4,q5,q6,q7;
    const unsigned* ap = hb + slotC*SLOT_STRIDE
                       + ((unsigned)(b0g + (l & 7)) << 10)
                       + (unsigned)(v*128 + ((l >> 4) << 3));
    for (;;) {
      int ok;
      if ((l & 15) < 8) {
        asm volatile(
          "global_load_dwordx4 %0, %8, off sc0 sc1\n\t"
          "global_load_dwordx4 %1, %8, off offset:16 sc0 sc1\n\t"
          "global_load_dwordx4 %2, %8, off offset:128 sc0 sc1\n\t"
          "global_load_dwordx4 %3, %8, off offset:144 sc0 sc1\n\t"
          "global_load_dwordx4 %4, %8, off offset:256 sc0 sc1\n\t"
          "global_load_dwordx4 %5, %8, off offset:272 sc0 sc1\n\t"
          "global_load_dwordx4 %6, %8, off offset:384 sc0 sc1\n\t"
          "global_load_dwordx4 %7, %8, off offset:400 sc0 sc1\n\t"
          "s_waitcnt vmcnt(0)"
          : "=&v"(q0), "=&v"(q1), "=&v"(q2), "=&v"(q3),
            "=&v"(q4), "=&v"(q5), "=&v"(q6), "=&v"(q7)
          : "v"(ap) : "memory");
        ok = ((q0.x & 7u) == tagC) & ((q1.x & 7u) == tagC) &
             ((q2.x & 7u) == tagC) & ((q3.x & 7u) == tagC) &
             ((q4.x & 7u) == tagC) & ((q5.x & 7u) == tagC) &
             ((q6.x & 7u) == tagC) & ((q7.x & 7u) == tagC);
      } else ok = 1;
      if (__all(ok)) break;
      __builtin_amdgcn_s_sleep(2);
    }
    f32x4 accy = {0.f,0.f,0.f,0.f};
#pragma unroll
    for (int i = 0; i < 4; ++i) {
      u32x4 qa = (i==0) ? q0 : (i==1) ? q2 : (i==2) ? q4 : q6;
      u32x4 qb = (i==0) ? q1 : (i==1) ? q3 : (i==2) ? q5 : q7;
      s16x8 ah = pack_hi(qa, qb), al = pack_lo(qa, qb);
      accy = MFMA16(ah, woh[i], accy, 0,0,0);
      accy = MFMA16(al, woh[i], accy, 0,0,0);
      accy = MFMA16(ah, wol[i], accy, 0,0,0);
    }
    if (l < 32 && (l & 15) < 8) {
      const int brow = (l >> 4) * 4, l15 = l & 15;
      float* scyp = &scy[v][brow][l15];
#pragma unroll
      for (int qq = 0; qq < 4; ++qq) scyp[qq*9] = accy[qq];
    }
    __syncthreads();
    if (l < 8) {
      float s = wob_s;
#pragma unroll
      for (int k2 = 0; k2 < 8; ++k2) s += scy[k2][v][le];
      out[((size_t)gb_v*S_DIM + (S_DIM-1))*OUT_DIM + w*8 + le] = s;
    }
  }
}

extern "C" void kernel_launch(void* const* d_in, const int* in_sizes, int n_in,
                              void* d_out, int out_size, void* d_ws, size_t ws_size,
                              hipStream_t stream) {
  const float* x    = (const float*)d_in[0];
  const float* h0   = (const float*)d_in[1];
  const float* ts   = (const float*)d_in[2];
  const float* tau  = (const float*)d_in[3];
  const float* Wiw  = (const float*)d_in[4];
  const float* Wib  = (const float*)d_in[5];
  const float* Wrw  = (const float*)d_in[6];
  const float* msk  = (const float*)d_in[7];
  const float* Wow  = (const float*)d_in[8];
  const float* Wob  = (const float*)d_in[9];
  const float* alp  = (const float*)d_in[10];
  const float* bet  = (const float*)d_in[11];
  const float* mu   = (const float*)d_in[12];
  const float* sg   = (const float*)d_in[13];
  float* out = (float*)d_out;
  unsigned* hb = (unsigned*)d_ws;   // 2 slots x 256KB tagged h exchange

  // poison every tag (field=7 never valid) -> replay-deterministic, no flags needed
  hipMemsetAsync(hb, 0xFF, 2*SLOT_STRIDE*sizeof(unsigned), stream);

  void* args[] = { (void*)&x, (void*)&h0, (void*)&ts, (void*)&tau,
                   (void*)&Wiw, (void*)&Wib, (void*)&Wrw, (void*)&msk,
                   (void*)&Wow, (void*)&Wob, (void*)&alp, (void*)&bet,
                   (void*)&mu, (void*)&sg, (void*)&out, (void*)&hb };
  hipLaunchCooperativeKernel((const void*)ltc_kernel, dim3(NWG), dim3(NTHREADS),
                             args, 0, stream);
}